// Round 7
// baseline (207.105 us; speedup 1.0000x reference)
//
#include <hip/hip_runtime.h>
#include <hip/hip_bf16.h>
#include <hip/hip_fp16.h>
#include <math.h>

// Problem constants
#define B_ 4
#define C_ 256
#define H_ 64
#define W_ 64
#define COMP_ 64
#define K2_ 25
#define HW_ (H_*W_)   // 4096
#define EPS_ 1e-5f

typedef float v2f __attribute__((ext_vector_type(2)));
typedef float f32x4 __attribute__((ext_vector_type(4)));
typedef _Float16 half8 __attribute__((ext_vector_type(8)));
#define FMA2(a, b, c) __builtin_elementwise_fma((a), (b), (c))

// ---------------------------------------------------------------------------
// Kernel T: weight layout transforms (unchanged).
// ---------------------------------------------------------------------------
__global__ void k_transpose(const float* __restrict__ w_comp,
                            const float* __restrict__ w_enc,
                            float* __restrict__ wTc,
                            __half* __restrict__ Apack) {
    int t = blockIdx.x * 256 + threadIdx.x;
    if (t < COMP_ * C_) {
        int o = t & 63;
        int c = t >> 6;
        wTc[t] = w_comp[o * C_ + c];
    } else {
        int t2 = t - COMP_ * C_;
        if (t2 < 8 * 18 * 64) {                     // 9216 fragment slots
            int lane = t2 & 63;
            int ks   = (t2 >> 6) % 18;
            int MT   = t2 / (64 * 18);
            int m    = MT * 16 + (lane & 15);
            __half vals[8];
#pragma unroll
            for (int e = 0; e < 8; ++e) {
                int k = ks * 32 + (lane >> 4) * 8 + e;
                int q = k >> 6;                     // 0..8 (ky*3+kx)
                int c = k & 63;
                float wv = (m < 100) ? w_enc[(m * COMP_ + c) * 9 + q] : 0.f;
                vals[e] = __float2half(wv);
            }
            *(float4*)&Apack[(size_t)t2 * 8] = *(float4*)vals;
        }
    }
}

// ---------------------------------------------------------------------------
// Kernel A (v3, unchanged): 1x1 compression + BN + SiLU -> fp16 act16[b][px][c].
// ---------------------------------------------------------------------------
__global__ void __launch_bounds__(512)
k_compress(const float* __restrict__ x, const float* __restrict__ wTc,
           const float* __restrict__ gamma, const float* __restrict__ beta,
           const float* __restrict__ mean, const float* __restrict__ var,
           __half* __restrict__ act16) {
    __shared__ float sx[256 * 68];                 // 69,632 B
    const int tx = threadIdx.x;                    // px
    const int ty = threadIdx.y;                    // og (0..7)
    const int tid = ty * 64 + tx;
    const int ogu = __builtin_amdgcn_readfirstlane(ty);
    const int bb = blockIdx.y;
    const int p0 = blockIdx.x * 64;

    const float* xb = x + (size_t)bb * C_ * HW_ + p0;
#pragma unroll
    for (int l = 0; l < 8; ++l) {
        int e = tid + l * 512;                     // 0..4095
        int c = e >> 4;
        int p4 = (e & 15) << 2;
        float4 v4 = *(const float4*)(xb + (size_t)c * HW_ + p4);
        *(float4*)&sx[c * 68 + p4] = v4;
    }
    __syncthreads();

    v2f acc2[4];
#pragma unroll
    for (int k = 0; k < 4; ++k) acc2[k] = (v2f){0.f, 0.f};

#pragma unroll 8
    for (int c = 0; c < 256; ++c) {
        float xv = sx[c * 68 + tx];
        const v2f* w2 = (const v2f*)(wTc + c * COMP_ + ogu * 8);  // uniform -> s_load
        v2f xv2 = (v2f){xv, xv};
#pragma unroll
        for (int k = 0; k < 4; ++k)
            acc2[k] = FMA2(xv2, w2[k], acc2[k]);
    }

    // BN + SiLU -> fp16, repack to px-major via LDS (stride 68 halfs: 2-way banks)
    __half h8[8];
#pragma unroll
    for (int k = 0; k < 4; ++k) {
#pragma unroll
        for (int h = 0; h < 2; ++h) {
            int o = ty * 8 + 2 * k + h;
            float sv = (h == 0) ? acc2[k].x : acc2[k].y;
            float iv = gamma[o] * rsqrtf(var[o] + EPS_);
            float bn = (sv - mean[o]) * iv + beta[o];
            float sg = 1.f / (1.f + __expf(-bn));
            h8[2 * k + h] = __float2half(bn * sg);
        }
    }
    __syncthreads();                               // sx reads done
    __half* sxh = (__half*)sx;                     // [px][68] halfs
    *(float2*)&sxh[tx * 68 + ty * 8]     = *(float2*)&h8[0];
    *(float2*)&sxh[tx * 68 + ty * 8 + 4] = *(float2*)&h8[4];
    __syncthreads();

    // coalesced copy-out: 512 x 16B, dst fully contiguous 8 KB
    {
        int px = tid >> 3, c8 = tid & 7;
        float2 alo = *(float2*)&sxh[px * 68 + c8 * 8];
        float2 ahi = *(float2*)&sxh[px * 68 + c8 * 8 + 4];
        float4 v = make_float4(alo.x, alo.y, ahi.x, ahi.y);
        __half* ao = act16 + ((size_t)bb * HW_ + p0 + px) * COMP_ + c8 * 8;
        *(float4*)ao = v;
    }
}

// ---------------------------------------------------------------------------
// Kernel B (v4, unchanged): MFMA encoder, j split across grid.
// ---------------------------------------------------------------------------
__global__ void __launch_bounds__(512)
k_encoder(const __half* __restrict__ act16, const __half* __restrict__ Apack,
          __half* __restrict__ maskT) {
    __shared__ __align__(16) __half sact[3 * 34 * 80];   // 16,320 B (160 B/slot)
    __shared__ float cbuf[32 * 129];                      // 16,512 B
    __shared__ __align__(16) __half st[32 * 100];         // 6,400 B
    const int tid = threadIdx.x;
    const int i = blockIdx.x, b = blockIdx.y, jh = blockIdx.z;
    const int lane = tid & 63, w = tid >> 6;

    // ---- stage act rows i-1..i+1, col slots 0..33 (gj = jh*32 + s - 1) ----
    const __half* ab = act16 + (size_t)b * HW_ * COMP_;
    for (int t = tid; t < 3 * 34 * 8; t += 512) {
        int c8 = t & 7;
        int s  = (t >> 3) % 34;
        int r  = t / (34 * 8);
        int gi = i + r - 1;
        int gj = jh * 32 + s - 1;
        float4 v = make_float4(0.f, 0.f, 0.f, 0.f);
        if ((unsigned)gi < 64u && (unsigned)gj < 64u)
            v = *(const float4*)(ab + ((size_t)gi * 64 + gj) * COMP_ + c8 * 8);
        *(float4*)((char*)sact + (size_t)(r * 34 + s) * 160 + c8 * 16) = v;
    }
    __syncthreads();

    // ---- MFMA: 18 k-steps x 2 m-tiles per wave ----
    const int jloc0 = (w & 1) * 16;
    const int MT0   = (w >> 1) * 2;
    const int p = lane & 15, g = lane >> 4;
    f32x4 acc[2];
#pragma unroll
    for (int mt = 0; mt < 2; ++mt) acc[mt] = (f32x4){0.f, 0.f, 0.f, 0.f};
    const half8* Ap = (const half8*)Apack;
#pragma unroll
    for (int ks = 0; ks < 18; ++ks) {
        const int q = ks >> 1, ky = q / 3, kx = q % 3;      // compile-time
        half8 bf = *(const half8*)((const char*)sact +
                       (size_t)(ky * 34 + jloc0 + p + kx) * 160 +
                       ((ks & 1) * 32 + g * 8) * 2);
#pragma unroll
        for (int mt = 0; mt < 2; ++mt) {
            half8 af = Ap[((size_t)(MT0 + mt) * 18 + ks) * 64 + lane];
            acc[mt] = __builtin_amdgcn_mfma_f32_16x16x32_f16(af, bf, acc[mt], 0, 0, 0);
        }
    }

    // ---- C -> LDS transpose buffer [px 0..31][m pad129] ----
#pragma unroll
    for (int mt = 0; mt < 2; ++mt)
#pragma unroll
        for (int r4 = 0; r4 < 4; ++r4)
            cbuf[(jloc0 + p) * 129 + (MT0 + mt) * 16 + g * 4 + r4] = acc[mt][r4];
    __syncthreads();

    // ---- softmax over 25 taps (m = k2*4 + s2), 128 threads ----
    if (tid < 128) {
        int px = tid & 31, s2 = tid >> 5;
        float v[K2_];
        float mx = -1e30f;
#pragma unroll
        for (int k2 = 0; k2 < K2_; ++k2) {
            v[k2] = cbuf[px * 129 + k2 * 4 + s2];
            mx = fmaxf(mx, v[k2]);
        }
        float sum = 0.f;
#pragma unroll
        for (int k2 = 0; k2 < K2_; ++k2) { v[k2] = __expf(v[k2] - mx); sum += v[k2]; }
        float rs = 1.f / sum;
#pragma unroll
        for (int k2 = 0; k2 < K2_; ++k2)
            st[px * 100 + k2 * 4 + s2] = __float2half(v[k2] * rs);
    }
    __syncthreads();

    // ---- coalesced write: 32 px x 100 ch = 400 float4 of halfs ----
    float4* dst = (float4*)(maskT + ((size_t)b * HW_ + i * 64 + jh * 32) * 100);
    const float4* src = (const float4*)st;
    if (tid < 400) dst[tid] = src[tid];
}

// ---------------------------------------------------------------------------
// Kernel C (v6): persistent reassembly with MASK IN REGISTERS.
// grid 512 (b,i,cc-half; XCD-contiguous), block (64 px, 8) = 8 waves,
// __launch_bounds__(512,4) -> <=128 VGPR -> 2 blocks/CU (16 waves).
// ty = (s2-pair, ch-quad): thread owns 4 ch x 2 s2. Its mask slice
// (25 x v2f = 50 VGPR) is px-only -> loaded ONCE per block, reused for all
// 8 cc items. k2 loop: 1 ds_read_b128 (4ch x) + 4 FMA2 — zero mask LDS
// traffic (was b128+b64 per k2: LDS pipe ~24us/CU -> ~16us).
// Mask staged through sx[1] (dead before first WRITEX(1)); LDS 54.4 KB.
// x tiles register-staged double-buffered as v5 (T14). Bit-identical math.
// ---------------------------------------------------------------------------
__global__ void __launch_bounds__(512, 4)
k_reassemble(const float* __restrict__ x, const __half* __restrict__ maskT,
             float* __restrict__ out) {
    __shared__ float sx[2][5 * 68 * 20];           // 2 x 27.2 KB, [col][16ch+4pad]
    const int tx = threadIdx.x;                    // px / j (lane)
    const int ty = threadIdx.y;                    // (s2-pair, ch-quad)
    const int tid = ty * 64 + tx;
    const int s2p = ty & 1;                        // 0 -> s2{0,1}, 1 -> s2{2,3}
    const int chq = ty >> 1;                       // ch-quad 0..3

    const int bid = blockIdx.x;                    // 0..511
    const int id  = ((bid & 7) << 6) | (bid >> 3); // XCD gets 64 consecutive ids
    const int half = id & 1;
    const int i    = (id >> 1) & 63;
    const int b    = id >> 7;
    const int cc0  = half * 8;

    // ---- x-gather decode (cc-independent): LDS offset, validity, global off ----
    int    offs[3];
    size_t goff[3];
    bool   vld[3];
#pragma unroll
    for (int l = 0; l < 3; ++l) {
        int e = tid + l * 512;                     // 0..1535, valid < 1360
        int q = e / 340;
        int rem = e - q * 340;
        int r = rem / 68;
        int col = rem - r * 68;
        int gi = i + r - 2;
        int gj = col - 2;
        offs[l] = (r * 68 + col) * 20 + q * 4;
        vld[l]  = (e < 1360) && ((unsigned)gi < 64u) && ((unsigned)gj < 64u);
        goff[l] = (size_t)(q * 4) * HW_ + (size_t)gi * W_ + gj;  // guarded by vld
    }
    float4 vx[3];
    auto LOADX = [&](int cc) {
        const float* xit = x + ((size_t)b * C_ + cc * 16) * HW_;
#pragma unroll
        for (int l = 0; l < 3; ++l) {
            float4 v = make_float4(0.f, 0.f, 0.f, 0.f);
            if (vld[l]) {
                const float* p = xit + goff[l];
                v.x = p[0];
                v.y = p[HW_];
                v.z = p[2 * HW_];
                v.w = p[3 * HW_];
            }
            vx[l] = v;
        }
    };
    auto WRITEX = [&](int d) {
#pragma unroll
        for (int l = 0; l < 3; ++l) {
            int e = tid + l * 512;
            if (e < 1360) *(float4*)&sx[d][offs[l]] = vx[l];
        }
    };

    // ---- prologue ----
    LOADX(cc0);                                    // item-0 x loads in flight

    float* mbuf = &sx[1][0];                       // 6400 floats, dead after regs
    {
        const __half* mrow = maskT + ((size_t)b * HW_ + i * 64) * 100;
#pragma unroll
        for (int t = 0; t < 4; ++t) {
            int f = tid + t * 512;                 // float-group: 4 halfs each
            if (f < 1600) {
                float2 raw = *(const float2*)(mrow + f * 4);
                __half2 lo = ((const __half2*)&raw)[0];
                __half2 hi = ((const __half2*)&raw)[1];
                float2 flo = __half22float2(lo);
                float2 fhi = __half22float2(hi);
                int px = f / 25, k2 = f - px * 25; // f*4 = px*100 + k2*4 exactly
                *(float4*)&mbuf[k2 * 256 + px * 4] =
                    make_float4(flo.x, flo.y, fhi.x, fhi.y);
            }
        }
    }
    __syncthreads();                               // mbuf visible

    v2f mreg[K2_];                                 // 50 VGPRs: mask[px=tx][k2][s2p]
#pragma unroll
    for (int k2 = 0; k2 < K2_; ++k2)
        mreg[k2] = *(const v2f*)&mbuf[k2 * 256 + tx * 4 + s2p * 2];
    __syncthreads();                               // all mreg reads done (mbuf dies)

    WRITEX(0);
    __syncthreads();

    int dbuf = 0;
#pragma unroll 1
    for (int n = 0; n < 8; ++n) {
        const int cc = cc0 + n;
        if (n < 7) LOADX(cc + 1);                  // flies under compute(n)

        const float* sb = sx[dbuf];
        v2f acc[4];
#pragma unroll
        for (int cl = 0; cl < 4; ++cl) acc[cl] = (v2f){0.f, 0.f};

        // prefetch k2=0: 4 ch of x at (row 0, col tx)
        float4 xq = *(const float4*)&sb[(0 * 68 + tx + 0) * 20 + chq * 4];
#pragma unroll
        for (int k2 = 0; k2 < K2_; ++k2) {
            float4 xq_c = xq;
            if (k2 < K2_ - 1) {
                const int kn = k2 + 1;
                const int dy = kn / 5, dx = kn % 5;
                xq = *(const float4*)&sb[(dy * 68 + tx + dx) * 20 + chq * 4];
            }
            v2f m = mreg[k2];                      // registers — no LDS
            float xc[4] = {xq_c.x, xq_c.y, xq_c.z, xq_c.w};
#pragma unroll
            for (int cl = 0; cl < 4; ++cl) {
                v2f xv2 = (v2f){xc[cl], xc[cl]};
                acc[cl] = FMA2(xv2, m, acc[cl]);
            }
        }

        if (n < 7) WRITEX(dbuf ^ 1);               // vmcnt lands here (T14)

#pragma unroll
        for (int cl = 0; cl < 4; ++cl) {
            int c = cc * 16 + chq * 4 + cl;
            float* op = out + (((size_t)(b * C_ + c) * 128 + 2 * i + s2p) * 128) + 2 * tx;
            *(float2*)op = float2{acc[cl].x, acc[cl].y};
        }

        if (n < 7) __syncthreads();                // x(n+1) visible; 1 barrier/item
        dbuf ^= 1;
    }
}

// ---------------------------------------------------------------------------
extern "C" void kernel_launch(void* const* d_in, const int* in_sizes, int n_in,
                              void* d_out, int out_size, void* d_ws, size_t ws_size,
                              hipStream_t stream) {
    const float* x       = (const float*)d_in[0];
    const float* w_comp  = (const float*)d_in[1];
    const float* bn_g    = (const float*)d_in[2];
    const float* bn_b    = (const float*)d_in[3];
    const float* bn_m    = (const float*)d_in[4];
    const float* bn_v    = (const float*)d_in[5];
    const float* w_enc   = (const float*)d_in[6];
    float* out = (float*)d_out;

    float* ws     = (float*)d_ws;
    float* wTc    = ws;                              // 16,384 floats
    __half* Apack = (__half*)(ws + 16384);           // 73,728 halfs
    __half* act16 = (__half*)(ws + 53248);           // 1,048,576 halfs
    __half* maskT = (__half*)(ws + 577536);          // 1,638,400 halfs

    k_transpose<<<100, 256, 0, stream>>>(w_comp, w_enc, wTc, Apack);
    k_compress<<<dim3(64, B_), dim3(64, 8), 0, stream>>>(x, wTc, bn_g, bn_b, bn_m, bn_v, act16);
    k_encoder<<<dim3(64, B_, 2), 512, 0, stream>>>(act16, Apack, maskT);
    k_reassemble<<<512, dim3(64, 8), 0, stream>>>(x, maskT, out);
}

// Round 8
// 141.341 us; speedup vs baseline: 1.4653x; 1.4653x over previous
//
#include <hip/hip_runtime.h>
#include <hip/hip_bf16.h>
#include <hip/hip_fp16.h>
#include <math.h>

// Problem constants
#define B_ 4
#define C_ 256
#define H_ 64
#define W_ 64
#define COMP_ 64
#define K2_ 25
#define HW_ (H_*W_)   // 4096
#define EPS_ 1e-5f

typedef float v2f __attribute__((ext_vector_type(2)));
typedef float f32x4 __attribute__((ext_vector_type(4)));
typedef _Float16 half8 __attribute__((ext_vector_type(8)));
#define FMA2(a, b, c) __builtin_elementwise_fma((a), (b), (c))

// Async global->LDS (size must be a literal). LDS dest = uniform base + lane*size.
__device__ __forceinline__ void gload4(const void* g, void* l) {
    __builtin_amdgcn_global_load_lds((const __attribute__((address_space(1))) void*)g,
                                     (__attribute__((address_space(3))) void*)l, 4, 0, 0);
}
__device__ __forceinline__ void gload16(const void* g, void* l) {
    __builtin_amdgcn_global_load_lds((const __attribute__((address_space(1))) void*)g,
                                     (__attribute__((address_space(3))) void*)l, 16, 0, 0);
}

// ---------------------------------------------------------------------------
// Kernel T: weight layout transforms (unchanged).
// ---------------------------------------------------------------------------
__global__ void k_transpose(const float* __restrict__ w_comp,
                            const float* __restrict__ w_enc,
                            float* __restrict__ wTc,
                            __half* __restrict__ Apack) {
    int t = blockIdx.x * 256 + threadIdx.x;
    if (t < COMP_ * C_) {
        int o = t & 63;
        int c = t >> 6;
        wTc[t] = w_comp[o * C_ + c];
    } else {
        int t2 = t - COMP_ * C_;
        if (t2 < 8 * 18 * 64) {                     // 9216 fragment slots
            int lane = t2 & 63;
            int ks   = (t2 >> 6) % 18;
            int MT   = t2 / (64 * 18);
            int m    = MT * 16 + (lane & 15);
            __half vals[8];
#pragma unroll
            for (int e = 0; e < 8; ++e) {
                int k = ks * 32 + (lane >> 4) * 8 + e;
                int q = k >> 6;                     // 0..8 (ky*3+kx)
                int c = k & 63;
                float wv = (m < 100) ? w_enc[(m * COMP_ + c) * 9 + q] : 0.f;
                vals[e] = __float2half(wv);
            }
            *(float4*)&Apack[(size_t)t2 * 8] = *(float4*)vals;
        }
    }
}

// ---------------------------------------------------------------------------
// Kernel A (v3, unchanged): 1x1 compression + BN + SiLU -> fp16 act16[b][px][c].
// ---------------------------------------------------------------------------
__global__ void __launch_bounds__(512)
k_compress(const float* __restrict__ x, const float* __restrict__ wTc,
           const float* __restrict__ gamma, const float* __restrict__ beta,
           const float* __restrict__ mean, const float* __restrict__ var,
           __half* __restrict__ act16) {
    __shared__ float sx[256 * 68];                 // 69,632 B
    const int tx = threadIdx.x;                    // px
    const int ty = threadIdx.y;                    // og (0..7)
    const int tid = ty * 64 + tx;
    const int ogu = __builtin_amdgcn_readfirstlane(ty);
    const int bb = blockIdx.y;
    const int p0 = blockIdx.x * 64;

    const float* xb = x + (size_t)bb * C_ * HW_ + p0;
#pragma unroll
    for (int l = 0; l < 8; ++l) {
        int e = tid + l * 512;                     // 0..4095
        int c = e >> 4;
        int p4 = (e & 15) << 2;
        float4 v4 = *(const float4*)(xb + (size_t)c * HW_ + p4);
        *(float4*)&sx[c * 68 + p4] = v4;
    }
    __syncthreads();

    v2f acc2[4];
#pragma unroll
    for (int k = 0; k < 4; ++k) acc2[k] = (v2f){0.f, 0.f};

#pragma unroll 8
    for (int c = 0; c < 256; ++c) {
        float xv = sx[c * 68 + tx];
        const v2f* w2 = (const v2f*)(wTc + c * COMP_ + ogu * 8);  // uniform -> s_load
        v2f xv2 = (v2f){xv, xv};
#pragma unroll
        for (int k = 0; k < 4; ++k)
            acc2[k] = FMA2(xv2, w2[k], acc2[k]);
    }

    // BN + SiLU -> fp16, repack to px-major via LDS (stride 68 halfs: 2-way banks)
    __half h8[8];
#pragma unroll
    for (int k = 0; k < 4; ++k) {
#pragma unroll
        for (int h = 0; h < 2; ++h) {
            int o = ty * 8 + 2 * k + h;
            float sv = (h == 0) ? acc2[k].x : acc2[k].y;
            float iv = gamma[o] * rsqrtf(var[o] + EPS_);
            float bn = (sv - mean[o]) * iv + beta[o];
            float sg = 1.f / (1.f + __expf(-bn));
            h8[2 * k + h] = __float2half(bn * sg);
        }
    }
    __syncthreads();                               // sx reads done
    __half* sxh = (__half*)sx;                     // [px][68] halfs
    *(float2*)&sxh[tx * 68 + ty * 8]     = *(float2*)&h8[0];
    *(float2*)&sxh[tx * 68 + ty * 8 + 4] = *(float2*)&h8[4];
    __syncthreads();

    // coalesced copy-out: 512 x 16B, dst fully contiguous 8 KB
    {
        int px = tid >> 3, c8 = tid & 7;
        float2 alo = *(float2*)&sxh[px * 68 + c8 * 8];
        float2 ahi = *(float2*)&sxh[px * 68 + c8 * 8 + 4];
        float4 v = make_float4(alo.x, alo.y, ahi.x, ahi.y);
        __half* ao = act16 + ((size_t)bb * HW_ + p0 + px) * COMP_ + c8 * 8;
        *(float4*)ao = v;
    }
}

// ---------------------------------------------------------------------------
// Kernel B (v4, unchanged): MFMA encoder, j split across grid. (~8.5 us)
// ---------------------------------------------------------------------------
__global__ void __launch_bounds__(512)
k_encoder(const __half* __restrict__ act16, const __half* __restrict__ Apack,
          __half* __restrict__ maskT) {
    __shared__ __align__(16) __half sact[3 * 34 * 80];   // 16,320 B (160 B/slot)
    __shared__ float cbuf[32 * 129];                      // 16,512 B
    __shared__ __align__(16) __half st[32 * 100];         // 6,400 B
    const int tid = threadIdx.x;
    const int i = blockIdx.x, b = blockIdx.y, jh = blockIdx.z;
    const int lane = tid & 63, w = tid >> 6;

    // ---- stage act rows i-1..i+1, col slots 0..33 (gj = jh*32 + s - 1) ----
    const __half* ab = act16 + (size_t)b * HW_ * COMP_;
    for (int t = tid; t < 3 * 34 * 8; t += 512) {
        int c8 = t & 7;
        int s  = (t >> 3) % 34;
        int r  = t / (34 * 8);
        int gi = i + r - 1;
        int gj = jh * 32 + s - 1;
        float4 v = make_float4(0.f, 0.f, 0.f, 0.f);
        if ((unsigned)gi < 64u && (unsigned)gj < 64u)
            v = *(const float4*)(ab + ((size_t)gi * 64 + gj) * COMP_ + c8 * 8);
        *(float4*)((char*)sact + (size_t)(r * 34 + s) * 160 + c8 * 16) = v;
    }
    __syncthreads();

    // ---- MFMA: 18 k-steps x 2 m-tiles per wave ----
    const int jloc0 = (w & 1) * 16;
    const int MT0   = (w >> 1) * 2;
    const int p = lane & 15, g = lane >> 4;
    f32x4 acc[2];
#pragma unroll
    for (int mt = 0; mt < 2; ++mt) acc[mt] = (f32x4){0.f, 0.f, 0.f, 0.f};
    const half8* Ap = (const half8*)Apack;
#pragma unroll
    for (int ks = 0; ks < 18; ++ks) {
        const int q = ks >> 1, ky = q / 3, kx = q % 3;      // compile-time
        half8 bf = *(const half8*)((const char*)sact +
                       (size_t)(ky * 34 + jloc0 + p + kx) * 160 +
                       ((ks & 1) * 32 + g * 8) * 2);
#pragma unroll
        for (int mt = 0; mt < 2; ++mt) {
            half8 af = Ap[((size_t)(MT0 + mt) * 18 + ks) * 64 + lane];
            acc[mt] = __builtin_amdgcn_mfma_f32_16x16x32_f16(af, bf, acc[mt], 0, 0, 0);
        }
    }

    // ---- C -> LDS transpose buffer [px 0..31][m pad129] ----
#pragma unroll
    for (int mt = 0; mt < 2; ++mt)
#pragma unroll
        for (int r4 = 0; r4 < 4; ++r4)
            cbuf[(jloc0 + p) * 129 + (MT0 + mt) * 16 + g * 4 + r4] = acc[mt][r4];
    __syncthreads();

    // ---- softmax over 25 taps (m = k2*4 + s2), 128 threads ----
    if (tid < 128) {
        int px = tid & 31, s2 = tid >> 5;
        float v[K2_];
        float mx = -1e30f;
#pragma unroll
        for (int k2 = 0; k2 < K2_; ++k2) {
            v[k2] = cbuf[px * 129 + k2 * 4 + s2];
            mx = fmaxf(mx, v[k2]);
        }
        float sum = 0.f;
#pragma unroll
        for (int k2 = 0; k2 < K2_; ++k2) { v[k2] = __expf(v[k2] - mx); sum += v[k2]; }
        float rs = 1.f / sum;
#pragma unroll
        for (int k2 = 0; k2 < K2_; ++k2)
            st[px * 100 + k2 * 4 + s2] = __float2half(v[k2] * rs);
    }
    __syncthreads();

    // ---- coalesced write: 32 px x 100 ch = 400 float4 of halfs ----
    float4* dst = (float4*)(maskT + ((size_t)b * HW_ + i * 64 + jh * 32) * 100);
    const float4* src = (const float4*)st;
    if (tid < 400) dst[tid] = src[tid];
}

// ---------------------------------------------------------------------------
// Kernel C (v3 RESURRECTED from R2 — accounting shows it ran ~31 us, the best
// reassemble measured; it was discarded on a mis-attributed regression).
// Persistent double-buffered: 512 blocks x 256 thr; block owns fixed row i
// (XCD gets 8 consecutive i's), loops 8 items (b x cc-pair). Staging via
// global_load_lds (fire-and-forget, no reg round-trip) into planar LDS
// [r][c][68]; halo cols/rows pre-zeroed once, never overwritten.
// Pipeline: vmcnt(0)+barrier -> issue stage(n+1) -> compute(n).
// ---------------------------------------------------------------------------
__global__ void __launch_bounds__(256)
k_reassemble(const float* __restrict__ x, const __half* __restrict__ maskT,
             float* __restrict__ out) {
    __shared__ float sxp[2][5][16][68];               // 43,520 B
    __shared__ __align__(16) __half smaskp[2][6400];  // 25,600 B
    const int tx = threadIdx.x;                    // j (= lane)
    const int ty = threadIdx.y;                    // wave id / ch-quad
    const int tid = ty * 64 + tx;

    const int bid = blockIdx.x;                    // 0..511
    const int xcd = bid & 7;
    const int kk  = bid >> 3;                      // 0..63
    const int i   = xcd * 8 + (kk & 7);            // 8 consecutive i per XCD
    const int bc  = kk >> 3;                       // 0..7 -> cc pair {2bc, 2bc+1}

    // ---- prologue: zero halo cols {0,1,66,67} in both buffers ----
    for (int e = tid; e < 640; e += 256) {
        int d = e / 320; int rem = e - d * 320;
        int r = rem >> 6; int rem2 = rem & 63;
        int c = rem2 >> 2; int q = rem2 & 3;
        int col = (q & 1) + (q >> 1) * 66;         // 0,1,66,67
        sxp[d][r][c][col] = 0.f;
    }
    // ---- zero out-of-image row planes (constant per block since i fixed) ----
#pragma unroll
    for (int r = 0; r < 5; ++r) {
        int gi = i + r - 2;
        if ((unsigned)gi >= 64u) {
            for (int e = tid; e < 2 * 16 * 68; e += 256) {
                int d = e / 1088; int rem = e - d * 1088;
                int c = rem / 68; int col = rem - c * 68;
                sxp[d][r][c][col] = 0.f;
            }
        }
    }

    auto stage = [&](int n, int d) {
        const int b  = n >> 1;
        const int cc = bc * 2 + (n & 1);
        const float* xit = x + ((size_t)b * C_ + cc * 16) * HW_;
#pragma unroll
        for (int r = 0; r < 5; ++r) {
            int gi = i + r - 2;
            if ((unsigned)gi < 64u) {              // uniform branch
#pragma unroll
                for (int c4 = 0; c4 < 4; ++c4) {
                    int c = (ty << 2) + c4;        // wave-uniform
                    gload4(xit + (size_t)c * HW_ + gi * W_ + tx, &sxp[d][r][c][2]);
                }
            }
        }
        // mask row: 12800 B = 12 x 1KB (width16) + 2 x 256B (width4)
        const char* mrow = (const char*)(maskT + ((size_t)b * HW_ + i * 64) * 100);
        char* mdst = (char*)&smaskp[d][0];
        if (ty < 3) {
#pragma unroll
            for (int m = 0; m < 4; ++m) {
                int mi = ty * 4 + m;
                gload16(mrow + mi * 1024 + tx * 16, mdst + mi * 1024);
            }
        } else {
            gload4(mrow + 12288 + tx * 4, mdst + 12288);
            gload4(mrow + 12544 + tx * 4, mdst + 12544);
        }
    };

    stage(0, 0);

#pragma unroll 1
    for (int n = 0; n < 8; ++n) {
        const int d = n & 1;
        asm volatile("s_waitcnt vmcnt(0)" ::: "memory");  // stage(n) landed
        __syncthreads();
        if (n + 1 < 8) stage(n + 1, d ^ 1);               // flies under compute(n)

        const int b  = n >> 1;
        const int cc = bc * 2 + (n & 1);

        v2f a01[4], a23[4];
#pragma unroll
        for (int cl = 0; cl < 4; ++cl) { a01[cl] = (v2f){0.f, 0.f}; a23[cl] = (v2f){0.f, 0.f}; }

#pragma unroll
        for (int k2 = 0; k2 < K2_; ++k2) {
            const int dy = k2 / 5, dx = k2 % 5;
            __half2 h01 = *(const __half2*)&smaskp[d][tx * 100 + k2 * 4];
            __half2 h23 = *(const __half2*)&smaskp[d][tx * 100 + k2 * 4 + 2];
            float2 f01 = __half22float2(h01);
            float2 f23 = __half22float2(h23);
            v2f m01 = (v2f){f01.x, f01.y};
            v2f m23 = (v2f){f23.x, f23.y};
#pragma unroll
            for (int cl = 0; cl < 4; ++cl) {
                float xv = sxp[d][dy][(ty << 2) + cl][tx + dx];
                v2f xv2 = (v2f){xv, xv};
                a01[cl] = FMA2(xv2, m01, a01[cl]);
                a23[cl] = FMA2(xv2, m23, a23[cl]);
            }
        }

#pragma unroll
        for (int cl = 0; cl < 4; ++cl) {
            int c = cc * 16 + (ty << 2) + cl;
            float* op = out + (((size_t)(b * C_ + c) * 128 + 2 * i) * 128) + 2 * tx;
            *(float2*)op         = float2{a01[cl].x, a01[cl].y};
            *(float2*)(op + 128) = float2{a23[cl].x, a23[cl].y};
        }
    }
}

// ---------------------------------------------------------------------------
extern "C" void kernel_launch(void* const* d_in, const int* in_sizes, int n_in,
                              void* d_out, int out_size, void* d_ws, size_t ws_size,
                              hipStream_t stream) {
    const float* x       = (const float*)d_in[0];
    const float* w_comp  = (const float*)d_in[1];
    const float* bn_g    = (const float*)d_in[2];
    const float* bn_b    = (const float*)d_in[3];
    const float* bn_m    = (const float*)d_in[4];
    const float* bn_v    = (const float*)d_in[5];
    const float* w_enc   = (const float*)d_in[6];
    float* out = (float*)d_out;

    float* ws     = (float*)d_ws;
    float* wTc    = ws;                              // 16,384 floats
    __half* Apack = (__half*)(ws + 16384);           // 73,728 halfs
    __half* act16 = (__half*)(ws + 53248);           // 1,048,576 halfs
    __half* maskT = (__half*)(ws + 577536);          // 1,638,400 halfs

    k_transpose<<<100, 256, 0, stream>>>(w_comp, w_enc, wTc, Apack);
    k_compress<<<dim3(64, B_), dim3(64, 8), 0, stream>>>(x, wTc, bn_g, bn_b, bn_m, bn_v, act16);
    k_encoder<<<dim3(64, B_, 2), 512, 0, stream>>>(act16, Apack, maskT);
    k_reassemble<<<512, dim3(64, 4), 0, stream>>>(x, maskT, out);
}

// Round 10
// 140.021 us; speedup vs baseline: 1.4791x; 1.0094x over previous
//
#include <hip/hip_runtime.h>
#include <hip/hip_bf16.h>
#include <hip/hip_fp16.h>
#include <math.h>

// Problem constants
#define B_ 4
#define C_ 256
#define H_ 64
#define W_ 64
#define COMP_ 64
#define K2_ 25
#define HW_ (H_*W_)   // 4096
#define EPS_ 1e-5f

typedef float v2f __attribute__((ext_vector_type(2)));
typedef float f32x4 __attribute__((ext_vector_type(4)));
typedef _Float16 half8 __attribute__((ext_vector_type(8)));
#define FMA2(a, b, c) __builtin_elementwise_fma((a), (b), (c))

// Async global->LDS (size must be a literal). LDS dest = uniform base + lane*size.
__device__ __forceinline__ void gload4(const void* g, void* l) {
    __builtin_amdgcn_global_load_lds((const __attribute__((address_space(1))) void*)g,
                                     (__attribute__((address_space(3))) void*)l, 4, 0, 0);
}
__device__ __forceinline__ void gload16(const void* g, void* l) {
    __builtin_amdgcn_global_load_lds((const __attribute__((address_space(1))) void*)g,
                                     (__attribute__((address_space(3))) void*)l, 16, 0, 0);
}

// ---------------------------------------------------------------------------
// Kernel T: weight layout transforms (unchanged).
// ---------------------------------------------------------------------------
__global__ void k_transpose(const float* __restrict__ w_comp,
                            const float* __restrict__ w_enc,
                            float* __restrict__ wTc,
                            __half* __restrict__ Apack) {
    int t = blockIdx.x * 256 + threadIdx.x;
    if (t < COMP_ * C_) {
        int o = t & 63;
        int c = t >> 6;
        wTc[t] = w_comp[o * C_ + c];
    } else {
        int t2 = t - COMP_ * C_;
        if (t2 < 8 * 18 * 64) {                     // 9216 fragment slots
            int lane = t2 & 63;
            int ks   = (t2 >> 6) % 18;
            int MT   = t2 / (64 * 18);
            int m    = MT * 16 + (lane & 15);
            __half vals[8];
#pragma unroll
            for (int e = 0; e < 8; ++e) {
                int k = ks * 32 + (lane >> 4) * 8 + e;
                int q = k >> 6;                     // 0..8 (ky*3+kx)
                int c = k & 63;
                float wv = (m < 100) ? w_enc[(m * COMP_ + c) * 9 + q] : 0.f;
                vals[e] = __float2half(wv);
            }
            *(float4*)&Apack[(size_t)t2 * 8] = *(float4*)vals;
        }
    }
}

// ---------------------------------------------------------------------------
// Kernel A (v3, unchanged): 1x1 compression + BN + SiLU -> fp16 act16[b][px][c].
// ---------------------------------------------------------------------------
__global__ void __launch_bounds__(512)
k_compress(const float* __restrict__ x, const float* __restrict__ wTc,
           const float* __restrict__ gamma, const float* __restrict__ beta,
           const float* __restrict__ mean, const float* __restrict__ var,
           __half* __restrict__ act16) {
    __shared__ float sx[256 * 68];                 // 69,632 B
    const int tx = threadIdx.x;                    // px
    const int ty = threadIdx.y;                    // og (0..7)
    const int tid = ty * 64 + tx;
    const int ogu = __builtin_amdgcn_readfirstlane(ty);
    const int bb = blockIdx.y;
    const int p0 = blockIdx.x * 64;

    const float* xb = x + (size_t)bb * C_ * HW_ + p0;
#pragma unroll
    for (int l = 0; l < 8; ++l) {
        int e = tid + l * 512;                     // 0..4095
        int c = e >> 4;
        int p4 = (e & 15) << 2;
        float4 v4 = *(const float4*)(xb + (size_t)c * HW_ + p4);
        *(float4*)&sx[c * 68 + p4] = v4;
    }
    __syncthreads();

    v2f acc2[4];
#pragma unroll
    for (int k = 0; k < 4; ++k) acc2[k] = (v2f){0.f, 0.f};

#pragma unroll 8
    for (int c = 0; c < 256; ++c) {
        float xv = sx[c * 68 + tx];
        const v2f* w2 = (const v2f*)(wTc + c * COMP_ + ogu * 8);  // uniform -> s_load
        v2f xv2 = (v2f){xv, xv};
#pragma unroll
        for (int k = 0; k < 4; ++k)
            acc2[k] = FMA2(xv2, w2[k], acc2[k]);
    }

    // BN + SiLU -> fp16, repack to px-major via LDS (stride 68 halfs: 2-way banks)
    __half h8[8];
#pragma unroll
    for (int k = 0; k < 4; ++k) {
#pragma unroll
        for (int h = 0; h < 2; ++h) {
            int o = ty * 8 + 2 * k + h;
            float sv = (h == 0) ? acc2[k].x : acc2[k].y;
            float iv = gamma[o] * rsqrtf(var[o] + EPS_);
            float bn = (sv - mean[o]) * iv + beta[o];
            float sg = 1.f / (1.f + __expf(-bn));
            h8[2 * k + h] = __float2half(bn * sg);
        }
    }
    __syncthreads();                               // sx reads done
    __half* sxh = (__half*)sx;                     // [px][68] halfs
    *(float2*)&sxh[tx * 68 + ty * 8]     = *(float2*)&h8[0];
    *(float2*)&sxh[tx * 68 + ty * 8 + 4] = *(float2*)&h8[4];
    __syncthreads();

    // coalesced copy-out: 512 x 16B, dst fully contiguous 8 KB
    {
        int px = tid >> 3, c8 = tid & 7;
        float2 alo = *(float2*)&sxh[px * 68 + c8 * 8];
        float2 ahi = *(float2*)&sxh[px * 68 + c8 * 8 + 4];
        float4 v = make_float4(alo.x, alo.y, ahi.x, ahi.y);
        __half* ao = act16 + ((size_t)bb * HW_ + p0 + px) * COMP_ + c8 * 8;
        *(float4*)ao = v;
    }
}

// ---------------------------------------------------------------------------
// Kernel B (v4, unchanged): MFMA encoder, j split across grid. (~8.5 us)
// ---------------------------------------------------------------------------
__global__ void __launch_bounds__(512)
k_encoder(const __half* __restrict__ act16, const __half* __restrict__ Apack,
          __half* __restrict__ maskT) {
    __shared__ __align__(16) __half sact[3 * 34 * 80];   // 16,320 B (160 B/slot)
    __shared__ float cbuf[32 * 129];                      // 16,512 B
    __shared__ __align__(16) __half st[32 * 100];         // 6,400 B
    const int tid = threadIdx.x;
    const int i = blockIdx.x, b = blockIdx.y, jh = blockIdx.z;
    const int lane = tid & 63, w = tid >> 6;

    // ---- stage act rows i-1..i+1, col slots 0..33 (gj = jh*32 + s - 1) ----
    const __half* ab = act16 + (size_t)b * HW_ * COMP_;
    for (int t = tid; t < 3 * 34 * 8; t += 512) {
        int c8 = t & 7;
        int s  = (t >> 3) % 34;
        int r  = t / (34 * 8);
        int gi = i + r - 1;
        int gj = jh * 32 + s - 1;
        float4 v = make_float4(0.f, 0.f, 0.f, 0.f);
        if ((unsigned)gi < 64u && (unsigned)gj < 64u)
            v = *(const float4*)(ab + ((size_t)gi * 64 + gj) * COMP_ + c8 * 8);
        *(float4*)((char*)sact + (size_t)(r * 34 + s) * 160 + c8 * 16) = v;
    }
    __syncthreads();

    // ---- MFMA: 18 k-steps x 2 m-tiles per wave ----
    const int jloc0 = (w & 1) * 16;
    const int MT0   = (w >> 1) * 2;
    const int p = lane & 15, g = lane >> 4;
    f32x4 acc[2];
#pragma unroll
    for (int mt = 0; mt < 2; ++mt) acc[mt] = (f32x4){0.f, 0.f, 0.f, 0.f};
    const half8* Ap = (const half8*)Apack;
#pragma unroll
    for (int ks = 0; ks < 18; ++ks) {
        const int q = ks >> 1, ky = q / 3, kx = q % 3;      // compile-time
        half8 bf = *(const half8*)((const char*)sact +
                       (size_t)(ky * 34 + jloc0 + p + kx) * 160 +
                       ((ks & 1) * 32 + g * 8) * 2);
#pragma unroll
        for (int mt = 0; mt < 2; ++mt) {
            half8 af = Ap[((size_t)(MT0 + mt) * 18 + ks) * 64 + lane];
            acc[mt] = __builtin_amdgcn_mfma_f32_16x16x32_f16(af, bf, acc[mt], 0, 0, 0);
        }
    }

    // ---- C -> LDS transpose buffer [px 0..31][m pad129] ----
#pragma unroll
    for (int mt = 0; mt < 2; ++mt)
#pragma unroll
        for (int r4 = 0; r4 < 4; ++r4)
            cbuf[(jloc0 + p) * 129 + (MT0 + mt) * 16 + g * 4 + r4] = acc[mt][r4];
    __syncthreads();

    // ---- softmax over 25 taps (m = k2*4 + s2), 128 threads ----
    if (tid < 128) {
        int px = tid & 31, s2 = tid >> 5;
        float v[K2_];
        float mx = -1e30f;
#pragma unroll
        for (int k2 = 0; k2 < K2_; ++k2) {
            v[k2] = cbuf[px * 129 + k2 * 4 + s2];
            mx = fmaxf(mx, v[k2]);
        }
        float sum = 0.f;
#pragma unroll
        for (int k2 = 0; k2 < K2_; ++k2) { v[k2] = __expf(v[k2] - mx); sum += v[k2]; }
        float rs = 1.f / sum;
#pragma unroll
        for (int k2 = 0; k2 < K2_; ++k2)
            st[px * 100 + k2 * 4 + s2] = __float2half(v[k2] * rs);
    }
    __syncthreads();

    // ---- coalesced write: 32 px x 100 ch = 400 float4 of halfs ----
    float4* dst = (float4*)(maskT + ((size_t)b * HW_ + i * 64 + jh * 32) * 100);
    const float4* src = (const float4*)st;
    if (tid < 400) dst[tid] = src[tid];
}

// ---------------------------------------------------------------------------
// Kernel C (v3.2b): persistent double-buffered reassembly, LDS-instr dieted.
// vs v3 (38 us): (1) mask read = ONE ds_read_b64 per k2 (4 halfs contiguous,
// 8B-aligned; was 2x b32); (2) x reads share one base + const dword offsets
// {0,68,136,204} -> LLVM DS-combiner emits 2x ds_read2_b32 (was 4x b32);
// (3) mask staged only when b changes (items 2m,2m+1 share it), buffer
// (n>>1)&1 — writer != reader at every pipeline step, barrier-separated.
// 6 -> 3 LDS instr per k2; values and FMA order identical -> bit-identical.
// (Build fix vs R8 submission: braced init lists bound to named v2f vars
// before the FMA2 macro — commas inside {} split macro args.)
// ---------------------------------------------------------------------------
__global__ void __launch_bounds__(256)
k_reassemble(const float* __restrict__ x, const __half* __restrict__ maskT,
             float* __restrict__ out) {
    __shared__ float sxp[2][5][16][68];               // 43,520 B
    __shared__ __align__(16) __half smaskp[2][6400];  // 25,600 B
    const int tx = threadIdx.x;                    // j (= lane)
    const int ty = threadIdx.y;                    // wave id / ch-quad
    const int tid = ty * 64 + tx;

    const int bid = blockIdx.x;                    // 0..511
    const int xcd = bid & 7;
    const int kk  = bid >> 3;                      // 0..63
    const int i   = xcd * 8 + (kk & 7);            // 8 consecutive i per XCD
    const int bc  = kk >> 3;                       // 0..7 -> cc pair {2bc, 2bc+1}

    // ---- prologue: zero halo cols {0,1,66,67} in both buffers ----
    for (int e = tid; e < 640; e += 256) {
        int d = e / 320; int rem = e - d * 320;
        int r = rem >> 6; int rem2 = rem & 63;
        int c = rem2 >> 2; int q = rem2 & 3;
        int col = (q & 1) + (q >> 1) * 66;         // 0,1,66,67
        sxp[d][r][c][col] = 0.f;
    }
    // ---- zero out-of-image row planes (constant per block since i fixed) ----
#pragma unroll
    for (int r = 0; r < 5; ++r) {
        int gi = i + r - 2;
        if ((unsigned)gi >= 64u) {
            for (int e = tid; e < 2 * 16 * 68; e += 256) {
                int d = e / 1088; int rem = e - d * 1088;
                int c = rem / 68; int col = rem - c * 68;
                sxp[d][r][c][col] = 0.f;
            }
        }
    }

    auto stage = [&](int n, int d) {
        const int b  = n >> 1;
        const int cc = bc * 2 + (n & 1);
        const float* xit = x + ((size_t)b * C_ + cc * 16) * HW_;
#pragma unroll
        for (int r = 0; r < 5; ++r) {
            int gi = i + r - 2;
            if ((unsigned)gi < 64u) {              // uniform branch
#pragma unroll
                for (int c4 = 0; c4 < 4; ++c4) {
                    int c = (ty << 2) + c4;        // wave-uniform
                    gload4(xit + (size_t)c * HW_ + gi * W_ + tx, &sxp[d][r][c][2]);
                }
            }
        }
        if ((n & 1) == 0) {                        // new b -> stage mask once
            const char* mrow = (const char*)(maskT + ((size_t)b * HW_ + i * 64) * 100);
            char* mdst = (char*)&smaskp[b & 1][0];
            if (ty < 3) {
#pragma unroll
                for (int m = 0; m < 4; ++m) {
                    int mi = ty * 4 + m;
                    gload16(mrow + mi * 1024 + tx * 16, mdst + mi * 1024);
                }
            } else {
                gload4(mrow + 12288 + tx * 4, mdst + 12288);
                gload4(mrow + 12544 + tx * 4, mdst + 12544);
            }
        }
    };

    stage(0, 0);

#pragma unroll 1
    for (int n = 0; n < 8; ++n) {
        const int d = n & 1;
        const int md = (n >> 1) & 1;               // mask buffer for this b
        asm volatile("s_waitcnt vmcnt(0)" ::: "memory");  // stage(n) landed
        __syncthreads();
        if (n + 1 < 8) stage(n + 1, d ^ 1);               // flies under compute(n)

        const int b  = n >> 1;
        const int cc = bc * 2 + (n & 1);

        v2f a01[4], a23[4];
#pragma unroll
        for (int cl = 0; cl < 4; ++cl) { a01[cl] = (v2f){0.f, 0.f}; a23[cl] = (v2f){0.f, 0.f}; }

#pragma unroll
        for (int dy = 0; dy < 5; ++dy) {
#pragma unroll
            for (int dx = 0; dx < 5; ++dx) {
                const int k2 = dy * 5 + dx;
                // one ds_read_b64: 4 contiguous halfs, 8B-aligned
                float2 mraw = *(const float2*)&smaskp[md][tx * 100 + k2 * 4];
                __half2 h01 = ((const __half2*)&mraw)[0];
                __half2 h23 = ((const __half2*)&mraw)[1];
                float2 f01 = __half22float2(h01);
                float2 f23 = __half22float2(h23);
                v2f m01 = (v2f){f01.x, f01.y};
                v2f m23 = (v2f){f23.x, f23.y};
                // shared base + const dword offsets -> 2x ds_read2_b32
                const float* xc = &sxp[d][dy][ty << 2][tx + dx];
                float xv0 = xc[0];
                float xv1 = xc[68];
                float xv2 = xc[136];
                float xv3 = xc[204];
                v2f bx0 = (v2f){xv0, xv0};
                v2f bx1 = (v2f){xv1, xv1};
                v2f bx2 = (v2f){xv2, xv2};
                v2f bx3 = (v2f){xv3, xv3};
                a01[0] = FMA2(bx0, m01, a01[0]);
                a23[0] = FMA2(bx0, m23, a23[0]);
                a01[1] = FMA2(bx1, m01, a01[1]);
                a23[1] = FMA2(bx1, m23, a23[1]);
                a01[2] = FMA2(bx2, m01, a01[2]);
                a23[2] = FMA2(bx2, m23, a23[2]);
                a01[3] = FMA2(bx3, m01, a01[3]);
                a23[3] = FMA2(bx3, m23, a23[3]);
            }
        }

#pragma unroll
        for (int cl = 0; cl < 4; ++cl) {
            int c = cc * 16 + (ty << 2) + cl;
            float* op = out + (((size_t)(b * C_ + c) * 128 + 2 * i) * 128) + 2 * tx;
            *(float2*)op         = float2{a01[cl].x, a01[cl].y};
            *(float2*)(op + 128) = float2{a23[cl].x, a23[cl].y};
        }
    }
}

// ---------------------------------------------------------------------------
extern "C" void kernel_launch(void* const* d_in, const int* in_sizes, int n_in,
                              void* d_out, int out_size, void* d_ws, size_t ws_size,
                              hipStream_t stream) {
    const float* x       = (const float*)d_in[0];
    const float* w_comp  = (const float*)d_in[1];
    const float* bn_g    = (const float*)d_in[2];
    const float* bn_b    = (const float*)d_in[3];
    const float* bn_m    = (const float*)d_in[4];
    const float* bn_v    = (const float*)d_in[5];
    const float* w_enc   = (const float*)d_in[6];
    float* out = (float*)d_out;

    float* ws     = (float*)d_ws;
    float* wTc    = ws;                              // 16,384 floats
    __half* Apack = (__half*)(ws + 16384);           // 73,728 halfs
    __half* act16 = (__half*)(ws + 53248);           // 1,048,576 halfs
    __half* maskT = (__half*)(ws + 577536);          // 1,638,400 halfs

    k_transpose<<<100, 256, 0, stream>>>(w_comp, w_enc, wTc, Apack);
    k_compress<<<dim3(64, B_), dim3(64, 8), 0, stream>>>(x, wTc, bn_g, bn_b, bn_m, bn_v, act16);
    k_encoder<<<dim3(64, B_, 2), 512, 0, stream>>>(act16, Apack, maskT);
    k_reassemble<<<512, dim3(64, 4), 0, stream>>>(x, maskT, out);
}